// Round 2
// baseline (359.086 us; speedup 1.0000x reference)
//
#include <hip/hip_runtime.h>
#include <hip/hip_bf16.h>

typedef __bf16 bf16;
typedef __bf16 bf16x8 __attribute__((ext_vector_type(8)));
typedef float floatx4 __attribute__((ext_vector_type(4)));

#define B_ 2
#define T_ 2048
#define C_ 1024
#define H_ 16
#define D_ 64
#define M_ (B_ * T_) /* 4096 */

__device__ __forceinline__ void load_lds16(const void* g, void* l) {
  __builtin_amdgcn_global_load_lds(
      (const __attribute__((address_space(1))) unsigned int*)g,
      (__attribute__((address_space(3))) unsigned int*)l, 16, 0, 0);
}

// ------------------------------------------------------- fp32 -> bf16 convert
__global__ __launch_bounds__(256)
void cvt_f32_bf16(const float* __restrict__ in, bf16* __restrict__ out) {
  int i = (blockIdx.x * 256 + threadIdx.x) * 8;
  float4 a = *(const float4*)(in + i);
  float4 b = *(const float4*)(in + i + 4);
  bf16x8 o;
  o[0] = (bf16)a.x; o[1] = (bf16)a.y; o[2] = (bf16)a.z; o[3] = (bf16)a.w;
  o[4] = (bf16)b.x; o[5] = (bf16)b.y; o[6] = (bf16)b.z; o[7] = (bf16)b.w;
  *(bf16x8*)(out + i) = o;
}

// ------------------------------------------- transpose + convert (weights)
struct TP { const float* in[4]; bf16* out[4]; };

__global__ __launch_bounds__(256)
void transpose4(TP p) {
  __shared__ float tile[32][33];
  const float* in = p.in[blockIdx.z];
  bf16* out = p.out[blockIdx.z];
  int tx = threadIdx.x & 31, ty = threadIdx.x >> 5;
  int n0 = blockIdx.x * 32, k0 = blockIdx.y * 32;
#pragma unroll
  for (int j = 0; j < 32; j += 8)
    tile[ty + j][tx] = in[(size_t)(k0 + ty + j) * C_ + n0 + tx];
  __syncthreads();
#pragma unroll
  for (int j = 0; j < 32; j += 8)
    out[(size_t)(n0 + ty + j) * C_ + k0 + tx] = (bf16)tile[tx][ty + j];
}

// ---------------------------------------------------------------- GEMM
// C[M,N] = A[M,K](bf16) @ Bt[N,K]^T + bias(fp32).  128x128 tile, BK=64,
// 256 threads (4 waves, 2x2 of 64x64), 16x16x32 bf16 MFMA.
// LDS XOR-swizzle: logical chunk (row r, 16B-chunk c) stored at physical
// chunk r*8 + (c ^ (r&7)) -> conflict-light ds_read_b128, and staging stays
// compatible with global_load_lds's base+lane*16 contract.
template <typename OutT>
struct GArgs {
  const bf16* A; const bf16* Bt;
  const float* bias[3];
  OutT* Cout; int N; int K;
};

template <typename OutT>
__global__ __launch_bounds__(256, 2)
void gemm128(GArgs<OutT> g) {
  __shared__ __align__(16) bf16 As[128 * 64];
  __shared__ __align__(16) bf16 Bs[128 * 64];
  const int tid = threadIdx.x;
  const int wave = tid >> 6, lane = tid & 63;
  const int quad = lane >> 4, l16 = lane & 15;
  const int m0 = blockIdx.y * 128, n0 = blockIdx.x * 128;
  const int wm = (wave >> 1) * 64, wn = (wave & 1) * 64;

  floatx4 acc[4][4] = {};

  int rA[4], cA[4];
#pragma unroll
  for (int t = 0; t < 4; ++t) {
    int pch = (wave * 4 + t) * 64 + lane;
    rA[t] = pch >> 3;
    cA[t] = (pch & 7) ^ (rA[t] & 7);
  }

  for (int k0 = 0; k0 < g.K; k0 += 64) {
    __syncthreads();
#pragma unroll
    for (int t = 0; t < 4; ++t) {
      load_lds16(g.A + (size_t)(m0 + rA[t]) * g.K + k0 + cA[t] * 8,
                 As + (wave * 4 + t) * 512);
      load_lds16(g.Bt + (size_t)(n0 + rA[t]) * g.K + k0 + cA[t] * 8,
                 Bs + (wave * 4 + t) * 512);
    }
    __syncthreads();
#pragma unroll
    for (int s = 0; s < 2; ++s) {
      bf16x8 af[4], bfr[4];
#pragma unroll
      for (int i = 0; i < 4; ++i) {
        int mr = wm + i * 16 + l16;
        af[i] = *(const bf16x8*)(As + ((mr * 8) + ((s * 4 + quad) ^ (mr & 7))) * 8);
        int nr = wn + i * 16 + l16;
        bfr[i] = *(const bf16x8*)(Bs + ((nr * 8) + ((s * 4 + quad) ^ (nr & 7))) * 8);
      }
#pragma unroll
      for (int i = 0; i < 4; ++i)
#pragma unroll
        for (int j = 0; j < 4; ++j)
          acc[i][j] = __builtin_amdgcn_mfma_f32_16x16x32_bf16(af[i], bfr[j],
                                                              acc[i][j], 0, 0, 0);
    }
  }

#pragma unroll
  for (int j = 0; j < 4; ++j) {
    int col = n0 + wn + j * 16 + l16;
    const float* bp = g.bias[col >> 10];
    float bv = bp[col & 1023];
#pragma unroll
    for (int i = 0; i < 4; ++i) {
#pragma unroll
      for (int r = 0; r < 4; ++r) {
        int row = m0 + wm + i * 16 + quad * 4 + r;
        g.Cout[(size_t)row * g.N + col] = (OutT)(acc[i][j][r] + bv);
      }
    }
  }
}

// ---------------------------------------------------------------- attention
// grid (T/64, B*H); block 256 = 4 waves, each wave owns 16 Q rows.
// qkv: [4096][3072] bf16, cols [0,1024)=Q [1024,2048)=K [2048,3072)=V.
#define QKV_LD 3072

__global__ __launch_bounds__(256, 2)
void attn(const bf16* __restrict__ qkv, bf16* __restrict__ y) {
  __shared__ __align__(16) bf16 Kl[32][72];   // [tok][d], padded (16B-aligned rows)
  __shared__ __align__(16) bf16 Vt[64][40];   // [d][tok], padded (16B-aligned rows)
  __shared__ __align__(16) bf16 Pl[4][16][40];
  const int tid = threadIdx.x, wave = tid >> 6, lane = tid & 63;
  const int quad = lane >> 4, l16 = lane & 15;
  const int bh = blockIdx.y, b = bh >> 4, h = bh & 15;
  const int q0 = blockIdx.x * 64;
  const int qrow = q0 + wave * 16;
  const float slope = exp2f(-0.5f * (float)(h + 1));
  const float scale = 0.125f;
  const float L2E = 1.4426950408889634f;
  const float NINF = -__builtin_inff();

  bf16x8 qf[2];
  {
    const bf16* qp = qkv + (size_t)(b * T_ + qrow + l16) * QKV_LD + h * D_ + quad * 8;
    qf[0] = *(const bf16x8*)qp;
    qf[1] = *(const bf16x8*)(qp + 32);
  }
  float mrow[4], lrow[4];
  floatx4 o[4] = {};
#pragma unroll
  for (int r = 0; r < 4; ++r) { mrow[r] = NINF; lrow[r] = 0.f; }

  const int ntiles = q0 / 32 + 2;
  for (int t = 0; t < ntiles; ++t) {
    const int kj0 = t * 32;
    __syncthreads();
    {
      int tok = tid >> 3, dc = (tid & 7) * 8;
      size_t grow = (size_t)(b * T_ + kj0 + tok) * QKV_LD + h * D_ + dc;
      *(bf16x8*)(&Kl[tok][dc]) = *(const bf16x8*)(qkv + grow + 1024);
      bf16x8 vv = *(const bf16x8*)(qkv + grow + 2048);
#pragma unroll
      for (int j = 0; j < 8; ++j) Vt[dc + j][tok] = vv[j];
    }
    __syncthreads();
    if (kj0 > qrow + 15) continue;  // wave-uniform; barrier count stays balanced

    floatx4 sacc[2] = {};
#pragma unroll
    for (int s = 0; s < 2; ++s)
#pragma unroll
      for (int kt = 0; kt < 2; ++kt) {
        bf16x8 kf = *(const bf16x8*)(&Kl[kt * 16 + l16][s * 32 + quad * 8]);
        sacc[kt] = __builtin_amdgcn_mfma_f32_16x16x32_bf16(qf[s], kf, sacc[kt], 0, 0, 0);
      }

    float pv[2][4], tmax[4];
#pragma unroll
    for (int r = 0; r < 4; ++r) {
      int row = qrow + quad * 4 + r;
      float m2 = NINF;
#pragma unroll
      for (int kt = 0; kt < 2; ++kt) {
        int col = kj0 + kt * 16 + l16;
        float val = (col <= row)
                        ? sacc[kt][r] * scale + slope * (float)(col - row)
                        : NINF;
        pv[kt][r] = val;
        m2 = fmaxf(m2, val);
      }
      tmax[r] = m2;
    }
#pragma unroll
    for (int off = 1; off < 16; off <<= 1)
#pragma unroll
      for (int r = 0; r < 4; ++r)
        tmax[r] = fmaxf(tmax[r], __shfl_xor(tmax[r], off));

    float alpha[4], rsum[4];
#pragma unroll
    for (int r = 0; r < 4; ++r) {
      float mn = fmaxf(mrow[r], tmax[r]);
      alpha[r] = exp2f((mrow[r] - mn) * L2E);
      mrow[r] = mn;
      float s0 = 0.f;
#pragma unroll
      for (int kt = 0; kt < 2; ++kt) {
        float p = exp2f((pv[kt][r] - mn) * L2E);
        pv[kt][r] = p;
        s0 += p;
      }
      rsum[r] = s0;
    }
#pragma unroll
    for (int off = 1; off < 16; off <<= 1)
#pragma unroll
      for (int r = 0; r < 4; ++r)
        rsum[r] += __shfl_xor(rsum[r], off);
#pragma unroll
    for (int r = 0; r < 4; ++r) {
      lrow[r] = lrow[r] * alpha[r] + rsum[r];
#pragma unroll
      for (int nt = 0; nt < 4; ++nt) o[nt][r] *= alpha[r];
    }
    // C-layout -> A-layout via per-wave LDS round trip
#pragma unroll
    for (int kt = 0; kt < 2; ++kt)
#pragma unroll
      for (int r = 0; r < 4; ++r)
        Pl[wave][quad * 4 + r][kt * 16 + l16] = (bf16)pv[kt][r];

    bf16x8 pf = *(const bf16x8*)(&Pl[wave][l16][quad * 8]);
#pragma unroll
    for (int nt = 0; nt < 4; ++nt) {
      bf16x8 vf = *(const bf16x8*)(&Vt[nt * 16 + l16][quad * 8]);
      o[nt] = __builtin_amdgcn_mfma_f32_16x16x32_bf16(pf, vf, o[nt], 0, 0, 0);
    }
  }

#pragma unroll
  for (int r = 0; r < 4; ++r) {
    float inv = 1.f / lrow[r];
    int row = qrow + quad * 4 + r;
#pragma unroll
    for (int nt = 0; nt < 4; ++nt)
      y[(size_t)(b * T_ + row) * C_ + h * D_ + nt * 16 + l16] =
          (bf16)(o[nt][r] * inv);
  }
}

// ---------------------------------------------------------------- launch
extern "C" void kernel_launch(void* const* d_in, const int* in_sizes, int n_in,
                              void* d_out, int out_size, void* d_ws, size_t ws_size,
                              hipStream_t stream) {
  const float* x  = (const float*)d_in[0];
  const float* Wq = (const float*)d_in[1];
  const float* bq = (const float*)d_in[2];
  const float* Wk = (const float*)d_in[3];
  const float* bk = (const float*)d_in[4];
  const float* Wv = (const float*)d_in[5];
  const float* bv = (const float*)d_in[6];
  const float* Wo = (const float*)d_in[7];
  const float* bo = (const float*)d_in[8];

  bf16* ws  = (bf16*)d_ws;
  bf16* WtQ = ws;                              // [3072][1024] bf16: WtQ,WtK,WtV
  bf16* WtK = WtQ + (size_t)C_ * C_;
  bf16* WtV = WtK + (size_t)C_ * C_;
  bf16* WtO = WtV + (size_t)C_ * C_;
  bf16* xb  = WtO + (size_t)C_ * C_;           // [4096][1024] bf16
  bf16* qkv = xb + (size_t)M_ * C_;            // [4096][3072] bf16
  bf16* yb  = qkv + (size_t)M_ * 3 * C_;       // [4096][1024] bf16

  cvt_f32_bf16<<<dim3(M_ * C_ / (256 * 8)), 256, 0, stream>>>(x, xb);

  TP tp;
  tp.in[0] = Wq; tp.in[1] = Wk; tp.in[2] = Wv; tp.in[3] = Wo;
  tp.out[0] = WtQ; tp.out[1] = WtK; tp.out[2] = WtV; tp.out[3] = WtO;
  transpose4<<<dim3(32, 32, 4), 256, 0, stream>>>(tp);

  // fused QKV projection: [4096,1024] @ [1024,3072] -> bf16 qkv
  GArgs<bf16> gq;
  gq.A = xb; gq.Bt = WtQ;
  gq.bias[0] = bq; gq.bias[1] = bk; gq.bias[2] = bv;
  gq.Cout = qkv; gq.N = 3 * C_; gq.K = C_;
  gemm128<bf16><<<dim3(24, 32), 256, 0, stream>>>(gq);

  attn<<<dim3(T_ / 64, B_ * H_), 256, 0, stream>>>(qkv, yb);

  // output projection: [4096,1024] @ [1024,1024] -> fp32 d_out
  GArgs<float> go;
  go.A = yb; go.Bt = WtO;
  go.bias[0] = bo; go.bias[1] = bo; go.bias[2] = bo;
  go.Cout = (float*)d_out; go.N = C_; go.K = C_;
  gemm128<float><<<dim3(8, 32), 256, 0, stream>>>(go);
}

// Round 5
// 234.592 us; speedup vs baseline: 1.5307x; 1.5307x over previous
//
#include <hip/hip_runtime.h>
#include <hip/hip_bf16.h>

typedef __bf16 bf16;
typedef __bf16 bf16x2 __attribute__((ext_vector_type(2)));
typedef __bf16 bf16x8 __attribute__((ext_vector_type(8)));
typedef float floatx4 __attribute__((ext_vector_type(4)));

#define B_ 2
#define T_ 2048
#define C_ 1024
#define H_ 16
#define D_ 64
#define M_ 4096
#define QKV_LD 3072

__device__ __forceinline__ void load_lds16(const void* g, void* l) {
  __builtin_amdgcn_global_load_lds(
      (const __attribute__((address_space(1))) unsigned int*)g,
      (__attribute__((address_space(3))) unsigned int*)l, 16, 0, 0);
}

// ------------------------------------------------------- fp32 -> bf16 convert
__global__ __launch_bounds__(256)
void cvt_f32_bf16(const float* __restrict__ in, bf16* __restrict__ out) {
  int i = (blockIdx.x * 256 + threadIdx.x) * 8;
  float4 a = *(const float4*)(in + i);
  float4 b = *(const float4*)(in + i + 4);
  bf16x8 o;
  o[0] = (bf16)a.x; o[1] = (bf16)a.y; o[2] = (bf16)a.z; o[3] = (bf16)a.w;
  o[4] = (bf16)b.x; o[5] = (bf16)b.y; o[6] = (bf16)b.z; o[7] = (bf16)b.w;
  *(bf16x8*)(out + i) = o;
}

// ------------------------------------------- transpose + convert (weights)
struct TP { const float* in[4]; bf16* out[4]; };

__global__ __launch_bounds__(256)
void transpose4(TP p) {
  __shared__ float tile[32][33];
  const float* in = p.in[blockIdx.z];
  bf16* out = p.out[blockIdx.z];
  int tx = threadIdx.x & 31, ty = threadIdx.x >> 5;
  int n0 = blockIdx.x * 32, k0 = blockIdx.y * 32;
#pragma unroll
  for (int j = 0; j < 32; j += 8)
    tile[ty + j][tx] = in[(size_t)(k0 + ty + j) * C_ + n0 + tx];
  __syncthreads();
#pragma unroll
  for (int j = 0; j < 32; j += 8)
    out[(size_t)(n0 + ty + j) * C_ + k0 + tx] = (bf16)tile[tx][ty + j];
}

// ---------------------------------------------------------------- GEMM
template <typename OutT>
struct GArgs {
  const bf16* A; const bf16* Bt;
  const float* bias[3];
  OutT* Cout; int N; int K;
};

template <typename OutT>
__global__ __launch_bounds__(256, 2)
void gemm128(GArgs<OutT> g) {
  __shared__ __align__(16) bf16 As[128 * 64];
  __shared__ __align__(16) bf16 Bs[128 * 64];
  const int tid = threadIdx.x;
  const int wave = tid >> 6, lane = tid & 63;
  const int quad = lane >> 4, l16 = lane & 15;
  const int m0 = blockIdx.y * 128, n0 = blockIdx.x * 128;
  const int wm = (wave >> 1) * 64, wn = (wave & 1) * 64;

  floatx4 acc[4][4] = {};

  int rA[4], cA[4];
#pragma unroll
  for (int t = 0; t < 4; ++t) {
    int pch = (wave * 4 + t) * 64 + lane;
    rA[t] = pch >> 3;
    cA[t] = (pch & 7) ^ (rA[t] & 7);
  }

  for (int k0 = 0; k0 < g.K; k0 += 64) {
    __syncthreads();
#pragma unroll
    for (int t = 0; t < 4; ++t) {
      load_lds16(g.A + (size_t)(m0 + rA[t]) * g.K + k0 + cA[t] * 8,
                 As + (wave * 4 + t) * 512);
      load_lds16(g.Bt + (size_t)(n0 + rA[t]) * g.K + k0 + cA[t] * 8,
                 Bs + (wave * 4 + t) * 512);
    }
    __syncthreads();
#pragma unroll
    for (int s = 0; s < 2; ++s) {
      bf16x8 af[4], bfr[4];
#pragma unroll
      for (int i = 0; i < 4; ++i) {
        int mr = wm + i * 16 + l16;
        af[i] = *(const bf16x8*)(As + ((mr * 8) + ((s * 4 + quad) ^ (mr & 7))) * 8);
        int nr = wn + i * 16 + l16;
        bfr[i] = *(const bf16x8*)(Bs + ((nr * 8) + ((s * 4 + quad) ^ (nr & 7))) * 8);
      }
#pragma unroll
      for (int i = 0; i < 4; ++i)
#pragma unroll
        for (int j = 0; j < 4; ++j)
          acc[i][j] = __builtin_amdgcn_mfma_f32_16x16x32_bf16(af[i], bfr[j],
                                                              acc[i][j], 0, 0, 0);
    }
  }

#pragma unroll
  for (int j = 0; j < 4; ++j) {
    int col = n0 + wn + j * 16 + l16;
    const float* bp = g.bias[col >> 10];
    float bv = bp[col & 1023];
#pragma unroll
    for (int i = 0; i < 4; ++i) {
#pragma unroll
      for (int r = 0; r < 4; ++r) {
        int row = m0 + wm + i * 16 + quad * 4 + r;
        g.Cout[(size_t)row * g.N + col] = (OutT)(acc[i][j][r] + bv);
      }
    }
  }
}

// ------------------------------------------- V transpose: per head [T][64]->[64][T]
__global__ __launch_bounds__(256)
void vtrans(const bf16* __restrict__ qkv, bf16* __restrict__ vt) {
  __shared__ bf16 tile[64][72];
  const int bh = blockIdx.x, b = bh >> 4, h = bh & 15;
  const int t0 = blockIdx.y * 64;
  {
    const int tok = threadIdx.x >> 2, c = threadIdx.x & 3;
    const bf16* src = qkv + (size_t)(b * T_ + t0 + tok) * QKV_LD + 2048 + h * 64;
    *(bf16x8*)(&tile[tok][c * 8]) = *(const bf16x8*)(src + c * 8);
    *(bf16x8*)(&tile[tok][32 + c * 8]) = *(const bf16x8*)(src + 32 + c * 8);
  }
  __syncthreads();
  {
    const int d = threadIdx.x & 63, g = threadIdx.x >> 6;
    bf16x8 a, bb;
#pragma unroll
    for (int j = 0; j < 8; ++j) { a[j] = tile[g * 16 + j][d]; bb[j] = tile[g * 16 + 8 + j][d]; }
    bf16* dst = vt + (size_t)(bh * 64 + d) * T_ + t0 + g * 16;
    *(bf16x8*)dst = a;
    *(bf16x8*)(dst + 8) = bb;
  }
}

// ---------------------------------------------------------------- attention
// grid (32 bh, 8 qpairs); block 256 = 4 waves x 32 Q rows.  K-tile 64.
// Each block does q-tiles qb and 15-qb (perfect balance: 34 iters each).
// l-state rides a 5th accumulator via a ones B-fragment.
// NOTE: no wave-divergent skip — fully-masked subtiles contribute exactly 0
// (P=exp2(-inf)=0, alpha=1), keeping all waves convergent around barriers.
__global__ __launch_bounds__(256, 1)
void attn2(const bf16* __restrict__ qkv, const bf16* __restrict__ vt,
           bf16* __restrict__ y) {
  __shared__ __align__(16) bf16 Kl[64 * 64];
  __shared__ __align__(16) bf16 Vl[64 * 64];
  __shared__ __align__(16) bf16 Pl[4][64 * 18];
  const int tid = threadIdx.x, wave = tid >> 6, lane = tid & 63;
  const int quad = lane >> 4, l16 = lane & 15;
  const int bh = blockIdx.x, b = bh >> 4, h = bh & 15;
  const float L2E = 1.4426950408889634f;
  const float slope2 = exp2f(-0.5f * (float)(h + 1)) * L2E;  // log2-domain slope
  const float scl2 = 0.125f * L2E;
  const float NINF = -__builtin_inff();

  bf16x8 ones;
  {
    bf16 v1 = (l16 == 0) ? (bf16)1.0f : (bf16)0.0f;
#pragma unroll
    for (int j = 0; j < 8; ++j) ones[j] = v1;
  }

  int rS[2], cS[2];
#pragma unroll
  for (int t = 0; t < 2; ++t) {
    int p = t * 256 + tid;
    rS[t] = p >> 3;
    cS[t] = (p & 7) ^ (rS[t] & 7);
  }

  bf16* Plw = Pl[wave];

  for (int pq = 0; pq < 2; ++pq) {
    const int qb = pq ? (15 - (int)blockIdx.y) : (int)blockIdx.y;
    const int q0 = qb * 128;
    const int w0 = q0 + wave * 32;

    bf16x8 qf[2][2];
#pragma unroll
    for (int qt = 0; qt < 2; ++qt)
#pragma unroll
      for (int s = 0; s < 2; ++s)
        qf[qt][s] = *(const bf16x8*)(qkv +
            (size_t)(b * T_ + w0 + qt * 16 + l16) * QKV_LD + h * 64 + s * 32 + quad * 8);

    float mrow[2][4];
    floatx4 o[2][5];
#pragma unroll
    for (int qt = 0; qt < 2; ++qt) {
#pragma unroll
      for (int r = 0; r < 4; ++r) mrow[qt][r] = NINF;
#pragma unroll
      for (int n = 0; n < 5; ++n) o[qt][n] = (floatx4)0.f;
    }

    const int niter = qb * 2 + 2;
    for (int it = 0; it < niter; ++it) {
      const int kj0 = it * 64;
      __syncthreads();
#pragma unroll
      for (int t = 0; t < 2; ++t) {
        load_lds16(qkv + (size_t)(b * T_ + kj0 + rS[t]) * QKV_LD + 1024 + h * 64 + cS[t] * 8,
                   Kl + (t * 4 + wave) * 512);
        load_lds16(vt + (size_t)(bh * 64 + rS[t]) * T_ + kj0 + cS[t] * 8,
                   Vl + (t * 4 + wave) * 512);
      }
      __builtin_amdgcn_s_waitcnt(0x0f70);  // vmcnt(0): our LDS-bound loads landed
      __syncthreads();

      float scol[4];
#pragma unroll
      for (int kt = 0; kt < 4; ++kt)
        scol[kt] = slope2 * (float)(kj0 + kt * 16 + l16);

#pragma unroll
      for (int qt = 0; qt < 2; ++qt) {
        const int rb = w0 + qt * 16;
        floatx4 sa[4] = {};
#pragma unroll
        for (int ss = 0; ss < 2; ++ss)
#pragma unroll
          for (int kt = 0; kt < 4; ++kt) {
            const int krow = kt * 16 + l16;
            bf16x8 kf = *(const bf16x8*)(Kl + krow * 64 + (((ss * 4 + quad) ^ (krow & 7)) * 8));
            sa[kt] = __builtin_amdgcn_mfma_f32_16x16x32_bf16(qf[qt][ss], kf, sa[kt], 0, 0, 0);
          }

        // mask needed iff any col (kj0..kj0+63) exceeds any row (rb..rb+15)
        const bool diag = (kj0 + 63 > rb);
        float v[4][4], tm[4];
#pragma unroll
        for (int r = 0; r < 4; ++r) {
          const int row = rb + quad * 4 + r;
          float m2 = NINF;
#pragma unroll
          for (int kt = 0; kt < 4; ++kt) {
            float val = fmaf(sa[kt][r], scl2, scol[kt]);
            if (diag && (kj0 + kt * 16 + l16 > row)) val = NINF;
            v[kt][r] = val;
            m2 = fmaxf(m2, val);
          }
          tm[r] = m2;
        }
#pragma unroll
        for (int off = 1; off < 16; off <<= 1)
#pragma unroll
          for (int r = 0; r < 4; ++r)
            tm[r] = fmaxf(tm[r], __shfl_xor(tm[r], off));

        float al[4];
#pragma unroll
        for (int r = 0; r < 4; ++r) {
          float mn = fmaxf(mrow[qt][r], tm[r]);   // finite after it=0 even if tm=-inf
          al[r] = __builtin_amdgcn_exp2f(mrow[qt][r] - mn);
          mrow[qt][r] = mn;
        }
#pragma unroll
        for (int kt = 0; kt < 4; ++kt) {
          bf16x2 lo, hi;
          lo[0] = (bf16)__builtin_amdgcn_exp2f(v[kt][0] - mrow[qt][0]);
          lo[1] = (bf16)__builtin_amdgcn_exp2f(v[kt][1] - mrow[qt][1]);
          hi[0] = (bf16)__builtin_amdgcn_exp2f(v[kt][2] - mrow[qt][2]);
          hi[1] = (bf16)__builtin_amdgcn_exp2f(v[kt][3] - mrow[qt][3]);
          bf16* pp = Plw + (kt * 16 + l16) * 18 + quad * 4;
          *(bf16x2*)pp = lo;
          *(bf16x2*)(pp + 2) = hi;
        }
#pragma unroll
        for (int n = 0; n < 5; ++n)
#pragma unroll
          for (int r = 0; r < 4; ++r) o[qt][n][r] *= al[r];

        __builtin_amdgcn_s_waitcnt(0xc07f);  // lgkmcnt(0): P writes visible in-wave

#pragma unroll
        for (int half = 0; half < 2; ++half) {
          bf16x8 pf;
          const bf16* pr = Plw + (half * 32 + quad * 8) * 18 + l16;
#pragma unroll
          for (int j = 0; j < 8; ++j) pf[j] = pr[j * 18];
#pragma unroll
          for (int nt = 0; nt < 4; ++nt) {
            const int vrow = nt * 16 + l16;
            bf16x8 vf = *(const bf16x8*)(Vl + vrow * 64 + (((half * 4 + quad) ^ (vrow & 7)) * 8));
            o[qt][nt] = __builtin_amdgcn_mfma_f32_16x16x32_bf16(pf, vf, o[qt][nt], 0, 0, 0);
          }
          o[qt][4] = __builtin_amdgcn_mfma_f32_16x16x32_bf16(pf, ones, o[qt][4], 0, 0, 0);
        }
      }
    }

#pragma unroll
    for (int qt = 0; qt < 2; ++qt)
#pragma unroll
      for (int r = 0; r < 4; ++r) {
        float lsum = __shfl(o[qt][4][r], lane & 48);  // broadcast from l16==0 of quad
        float inv = 1.f / lsum;
        const int row = w0 + qt * 16 + quad * 4 + r;
#pragma unroll
        for (int nt = 0; nt < 4; ++nt)
          y[(size_t)(b * T_ + row) * C_ + h * 64 + nt * 16 + l16] =
              (bf16)(o[qt][nt][r] * inv);
      }
  }
}

// ---------------------------------------------------------------- launch
extern "C" void kernel_launch(void* const* d_in, const int* in_sizes, int n_in,
                              void* d_out, int out_size, void* d_ws, size_t ws_size,
                              hipStream_t stream) {
  const float* x  = (const float*)d_in[0];
  const float* Wq = (const float*)d_in[1];
  const float* bq = (const float*)d_in[2];
  const float* Wk = (const float*)d_in[3];
  const float* bk = (const float*)d_in[4];
  const float* Wv = (const float*)d_in[5];
  const float* bv = (const float*)d_in[6];
  const float* Wo = (const float*)d_in[7];
  const float* bo = (const float*)d_in[8];

  bf16* ws  = (bf16*)d_ws;
  bf16* WtQ = ws;                              // [3072][1024] bf16 + WtO
  bf16* WtK = WtQ + (size_t)C_ * C_;
  bf16* WtV = WtK + (size_t)C_ * C_;
  bf16* WtO = WtV + (size_t)C_ * C_;
  bf16* xb  = WtO + (size_t)C_ * C_;           // [4096][1024] bf16 (dead after QKV GEMM)
  bf16* vtb = xb;                              // [32][64][2048] bf16 overlays xb
  bf16* qkv = xb + (size_t)M_ * C_;            // [4096][3072] bf16
  bf16* yb  = qkv + (size_t)M_ * 3 * C_;       // [4096][1024] bf16

  cvt_f32_bf16<<<dim3(M_ * C_ / (256 * 8)), 256, 0, stream>>>(x, xb);

  TP tp;
  tp.in[0] = Wq; tp.in[1] = Wk; tp.in[2] = Wv; tp.in[3] = Wo;
  tp.out[0] = WtQ; tp.out[1] = WtK; tp.out[2] = WtV; tp.out[3] = WtO;
  transpose4<<<dim3(32, 32, 4), 256, 0, stream>>>(tp);

  GArgs<bf16> gq;
  gq.A = xb; gq.Bt = WtQ;
  gq.bias[0] = bq; gq.bias[1] = bk; gq.bias[2] = bv;
  gq.Cout = qkv; gq.N = 3 * C_; gq.K = C_;
  gemm128<bf16><<<dim3(24, 32), 256, 0, stream>>>(gq);

  vtrans<<<dim3(32, 32), 256, 0, stream>>>(qkv, vtb);

  attn2<<<dim3(32, 8), 256, 0, stream>>>(qkv, vtb, yb);

  GArgs<float> go;
  go.A = yb; go.Bt = WtO;
  go.bias[0] = bo; go.bias[1] = bo; go.bias[2] = bo;
  go.Cout = (float*)d_out; go.N = C_; go.K = C_;
  gemm128<float><<<dim3(8, 32), 256, 0, stream>>>(go);
}

// Round 6
// 225.859 us; speedup vs baseline: 1.5899x; 1.0387x over previous
//
#include <hip/hip_runtime.h>
#include <hip/hip_bf16.h>

typedef __bf16 bf16;
typedef __bf16 bf16x2 __attribute__((ext_vector_type(2)));
typedef __bf16 bf16x4 __attribute__((ext_vector_type(4)));
typedef __bf16 bf16x8 __attribute__((ext_vector_type(8)));
typedef float floatx4 __attribute__((ext_vector_type(4)));

#define B_ 2
#define T_ 2048
#define C_ 1024
#define H_ 16
#define D_ 64
#define M_ 4096
#define QK_LD 2048

__device__ __forceinline__ void load_lds16(const void* g, void* l) {
  __builtin_amdgcn_global_load_lds(
      (const __attribute__((address_space(1))) unsigned int*)g,
      (__attribute__((address_space(3))) unsigned int*)l, 16, 0, 0);
}

// ------------------------------------------------------- fp32 -> bf16 convert
__global__ __launch_bounds__(256)
void cvt_f32_bf16(const float* __restrict__ in, bf16* __restrict__ out) {
  int i = (blockIdx.x * 256 + threadIdx.x) * 8;
  float4 a = *(const float4*)(in + i);
  float4 b = *(const float4*)(in + i + 4);
  bf16x8 o;
  o[0] = (bf16)a.x; o[1] = (bf16)a.y; o[2] = (bf16)a.z; o[3] = (bf16)a.w;
  o[4] = (bf16)b.x; o[5] = (bf16)b.y; o[6] = (bf16)b.z; o[7] = (bf16)b.w;
  *(bf16x8*)(out + i) = o;
}

// ------------------------------------------- transpose + convert (weights)
struct TP { const float* in[4]; bf16* out[4]; };

__global__ __launch_bounds__(256)
void transpose4(TP p) {
  __shared__ float tile[32][33];
  const float* in = p.in[blockIdx.z];
  bf16* out = p.out[blockIdx.z];
  int tx = threadIdx.x & 31, ty = threadIdx.x >> 5;
  int n0 = blockIdx.x * 32, k0 = blockIdx.y * 32;
#pragma unroll
  for (int j = 0; j < 32; j += 8)
    tile[ty + j][tx] = in[(size_t)(k0 + ty + j) * C_ + n0 + tx];
  __syncthreads();
#pragma unroll
  for (int j = 0; j < 32; j += 8)
    out[(size_t)(n0 + ty + j) * C_ + k0 + tx] = (bf16)tile[tx][ty + j];
}

// ---------------------------------------------------------------- GEMM
// split mode: cols >=2048 (the V projection) are written transposed into
// vt[bh][d][T] (packed bf16x4 over 4 consecutive tokens); cols <2048 go to
// qk with leading dim g.N. Branch is wave-uniform (n0 is a multiple of 128).
template <typename OutT>
struct GArgs {
  const bf16* A; const bf16* Bt;
  const float* bias[3];
  OutT* Cout; bf16* vt; int N; int K; int split;
};

template <typename OutT>
__global__ __launch_bounds__(256, 2)
void gemm128(GArgs<OutT> g) {
  __shared__ __align__(16) bf16 As[128 * 64];
  __shared__ __align__(16) bf16 Bs[128 * 64];
  const int tid = threadIdx.x;
  const int wave = tid >> 6, lane = tid & 63;
  const int quad = lane >> 4, l16 = lane & 15;
  const int m0 = blockIdx.y * 128, n0 = blockIdx.x * 128;
  const int wm = (wave >> 1) * 64, wn = (wave & 1) * 64;

  floatx4 acc[4][4] = {};

  int rA[4], cA[4];
#pragma unroll
  for (int t = 0; t < 4; ++t) {
    int pch = (wave * 4 + t) * 64 + lane;
    rA[t] = pch >> 3;
    cA[t] = (pch & 7) ^ (rA[t] & 7);
  }

  for (int k0 = 0; k0 < g.K; k0 += 64) {
    __syncthreads();
#pragma unroll
    for (int t = 0; t < 4; ++t) {
      load_lds16(g.A + (size_t)(m0 + rA[t]) * g.K + k0 + cA[t] * 8,
                 As + (wave * 4 + t) * 512);
      load_lds16(g.Bt + (size_t)(n0 + rA[t]) * g.K + k0 + cA[t] * 8,
                 Bs + (wave * 4 + t) * 512);
    }
    __syncthreads();
#pragma unroll
    for (int s = 0; s < 2; ++s) {
      bf16x8 af[4], bfr[4];
#pragma unroll
      for (int i = 0; i < 4; ++i) {
        int mr = wm + i * 16 + l16;
        af[i] = *(const bf16x8*)(As + ((mr * 8) + ((s * 4 + quad) ^ (mr & 7))) * 8);
        int nr = wn + i * 16 + l16;
        bfr[i] = *(const bf16x8*)(Bs + ((nr * 8) + ((s * 4 + quad) ^ (nr & 7))) * 8);
      }
#pragma unroll
      for (int i = 0; i < 4; ++i)
#pragma unroll
        for (int j = 0; j < 4; ++j)
          acc[i][j] = __builtin_amdgcn_mfma_f32_16x16x32_bf16(af[i], bfr[j],
                                                              acc[i][j], 0, 0, 0);
    }
  }

  const bool vsplit = g.split && (n0 >= 2048);
#pragma unroll
  for (int j = 0; j < 4; ++j) {
    int col = n0 + wn + j * 16 + l16;
    const float* bp = g.bias[col >> 10];
    float bv = bp[col & 1023];
    if (vsplit) {
      int cv = col - 2048;  // cv = h*64 + d
      bf16* dst0 = g.vt + ((size_t)((m0 >> 11) * 16 + (cv >> 6)) * 64 + (cv & 63)) * (size_t)T_
                   + (m0 & 2047) + wm + quad * 4;
#pragma unroll
      for (int i = 0; i < 4; ++i) {
        bf16x4 pk;
#pragma unroll
        for (int r = 0; r < 4; ++r) pk[r] = (bf16)(acc[i][j][r] + bv);
        *(bf16x4*)(dst0 + i * 16) = pk;
      }
    } else {
#pragma unroll
      for (int i = 0; i < 4; ++i) {
#pragma unroll
        for (int r = 0; r < 4; ++r) {
          int row = m0 + wm + i * 16 + quad * 4 + r;
          g.Cout[(size_t)row * g.N + col] = (OutT)(acc[i][j][r] + bv);
        }
      }
    }
  }
}

// ---------------------------------------------------------------- attention
// grid (32 bh, 16 q-tiles); block 256 = 4 waves x 32 Q rows.  K-tile 64.
// qb = y<8 ? 15-y : y-8  => first 256 blocks are the long tiles; round-robin
// pairs long+short per CU (pair sum = 34 iters, constant).  2 blocks/CU.
// l-state rides a 5th accumulator via a ones B-fragment.  No wave-divergent
// barriers; fully-masked subtiles contribute exactly 0 (P=0, alpha=1).
__global__ __launch_bounds__(256, 2)
void attn3(const bf16* __restrict__ qk, const bf16* __restrict__ vt,
           bf16* __restrict__ y) {
  __shared__ __align__(16) bf16 Kl[64 * 64];
  __shared__ __align__(16) bf16 Vl[64 * 64];
  __shared__ __align__(16) bf16 Pl[4][16 * 68];  // per-wave [row16][col64+4]
  const int tid = threadIdx.x, wave = tid >> 6, lane = tid & 63;
  const int quad = lane >> 4, l16 = lane & 15;
  const int bh = blockIdx.x, b = bh >> 4, h = bh & 15;
  const int qb = (blockIdx.y < 8) ? 15 - (int)blockIdx.y : (int)blockIdx.y - 8;
  const float L2E = 1.4426950408889634f;
  const float slope2 = exp2f(-0.5f * (float)(h + 1)) * L2E;  // log2-domain slope
  const float scl2 = 0.125f * L2E;
  const float NINF = -__builtin_inff();

  bf16x8 ones;
  {
    bf16 v1 = (l16 == 0) ? (bf16)1.0f : (bf16)0.0f;
#pragma unroll
    for (int j = 0; j < 8; ++j) ones[j] = v1;
  }

  int rS[2], cS[2];
#pragma unroll
  for (int t = 0; t < 2; ++t) {
    int p = t * 256 + tid;
    rS[t] = p >> 3;
    cS[t] = (p & 7) ^ (rS[t] & 7);
  }

  bf16* Plw = Pl[wave];
  const int q0 = qb * 128;
  const int w0 = q0 + wave * 32;

  bf16x8 qf[2][2];
#pragma unroll
  for (int qt = 0; qt < 2; ++qt)
#pragma unroll
    for (int s = 0; s < 2; ++s)
      qf[qt][s] = *(const bf16x8*)(qk +
          (size_t)(b * T_ + w0 + qt * 16 + l16) * QK_LD + h * 64 + s * 32 + quad * 8);

  float mrow[2][4];
  floatx4 o[2][5];
#pragma unroll
  for (int qt = 0; qt < 2; ++qt) {
#pragma unroll
    for (int r = 0; r < 4; ++r) mrow[qt][r] = NINF;
#pragma unroll
    for (int n = 0; n < 5; ++n) o[qt][n] = (floatx4)0.f;
  }

  const int niter = qb * 2 + 2;
  for (int it = 0; it < niter; ++it) {
    const int kj0 = it * 64;
    __syncthreads();
#pragma unroll
    for (int t = 0; t < 2; ++t) {
      load_lds16(qk + (size_t)(b * T_ + kj0 + rS[t]) * QK_LD + 1024 + h * 64 + cS[t] * 8,
                 Kl + (t * 4 + wave) * 512);
      load_lds16(vt + ((size_t)bh * 64 + rS[t]) * T_ + kj0 + cS[t] * 8,
                 Vl + (t * 4 + wave) * 512);
    }
    __builtin_amdgcn_s_waitcnt(0x0f70);  // vmcnt(0): our LDS-bound loads landed
    __syncthreads();

    float scol[4];
#pragma unroll
    for (int kt = 0; kt < 4; ++kt)
      scol[kt] = slope2 * (float)(kj0 + kt * 16 + l16);

#pragma unroll
    for (int qt = 0; qt < 2; ++qt) {
      const int rb = w0 + qt * 16;
      floatx4 sa[4] = {};
#pragma unroll
      for (int ss = 0; ss < 2; ++ss)
#pragma unroll
        for (int kt = 0; kt < 4; ++kt) {
          const int krow = kt * 16 + l16;
          bf16x8 kf = *(const bf16x8*)(Kl + krow * 64 + (((ss * 4 + quad) ^ (krow & 7)) * 8));
          sa[kt] = __builtin_amdgcn_mfma_f32_16x16x32_bf16(qf[qt][ss], kf, sa[kt], 0, 0, 0);
        }

      // mask needed iff any col (kj0..kj0+63) exceeds any row (rb..rb+15)
      float v[4][4], tm[4];
      if (kj0 + 63 > rb) {
#pragma unroll
        for (int r = 0; r < 4; ++r) {
          const int row = rb + quad * 4 + r;
          float m2 = NINF;
#pragma unroll
          for (int kt = 0; kt < 4; ++kt) {
            float val = fmaf(sa[kt][r], scl2, scol[kt]);
            if (kj0 + kt * 16 + l16 > row) val = NINF;
            v[kt][r] = val;
            m2 = fmaxf(m2, val);
          }
          tm[r] = m2;
        }
      } else {
#pragma unroll
        for (int r = 0; r < 4; ++r) {
          float m2 = NINF;
#pragma unroll
          for (int kt = 0; kt < 4; ++kt) {
            float val = fmaf(sa[kt][r], scl2, scol[kt]);
            v[kt][r] = val;
            m2 = fmaxf(m2, val);
          }
          tm[r] = m2;
        }
      }
#pragma unroll
      for (int off = 1; off < 16; off <<= 1)
#pragma unroll
        for (int r = 0; r < 4; ++r)
          tm[r] = fmaxf(tm[r], __shfl_xor(tm[r], off));

      float al[4];
#pragma unroll
      for (int r = 0; r < 4; ++r) {
        float mn = fmaxf(mrow[qt][r], tm[r]);   // finite after it=0 even if tm=-inf
        al[r] = __builtin_amdgcn_exp2f(mrow[qt][r] - mn);
        mrow[qt][r] = mn;
      }
      // P store in A-layout [row][col] (stride 68: conflict-free scalar writes)
#pragma unroll
      for (int kt = 0; kt < 4; ++kt)
#pragma unroll
        for (int r = 0; r < 4; ++r)
          Plw[(quad * 4 + r) * 68 + kt * 16 + l16] =
              (bf16)__builtin_amdgcn_exp2f(v[kt][r] - mrow[qt][r]);
#pragma unroll
      for (int n = 0; n < 5; ++n)
#pragma unroll
        for (int r = 0; r < 4; ++r) o[qt][n][r] *= al[r];

      __builtin_amdgcn_s_waitcnt(0xc07f);  // lgkmcnt(0): P writes visible in-wave

#pragma unroll
      for (int half = 0; half < 2; ++half) {
        bf16x8 pf = *(const bf16x8*)(Plw + l16 * 68 + half * 32 + quad * 8);
#pragma unroll
        for (int nt = 0; nt < 4; ++nt) {
          const int vrow = nt * 16 + l16;
          bf16x8 vf = *(const bf16x8*)(Vl + vrow * 64 + (((half * 4 + quad) ^ (vrow & 7)) * 8));
          o[qt][nt] = __builtin_amdgcn_mfma_f32_16x16x32_bf16(pf, vf, o[qt][nt], 0, 0, 0);
        }
        o[qt][4] = __builtin_amdgcn_mfma_f32_16x16x32_bf16(pf, ones, o[qt][4], 0, 0, 0);
      }
    }
  }

#pragma unroll
  for (int qt = 0; qt < 2; ++qt)
#pragma unroll
    for (int r = 0; r < 4; ++r) {
      float lsum = __shfl(o[qt][4][r], lane & 48);  // broadcast from l16==0 of quad
      float inv = 1.f / lsum;
      const int row = w0 + qt * 16 + quad * 4 + r;
#pragma unroll
      for (int nt = 0; nt < 4; ++nt)
        y[(size_t)(b * T_ + row) * C_ + h * 64 + nt * 16 + l16] =
            (bf16)(o[qt][nt][r] * inv);
    }
}

// ---------------------------------------------------------------- launch
extern "C" void kernel_launch(void* const* d_in, const int* in_sizes, int n_in,
                              void* d_out, int out_size, void* d_ws, size_t ws_size,
                              hipStream_t stream) {
  const float* x  = (const float*)d_in[0];
  const float* Wq = (const float*)d_in[1];
  const float* bq = (const float*)d_in[2];
  const float* Wk = (const float*)d_in[3];
  const float* bk = (const float*)d_in[4];
  const float* Wv = (const float*)d_in[5];
  const float* bv = (const float*)d_in[6];
  const float* Wo = (const float*)d_in[7];
  const float* bo = (const float*)d_in[8];

  bf16* ws  = (bf16*)d_ws;
  bf16* WtQ = ws;                              // weights^T, bf16, [1024][1024] each
  bf16* WtK = WtQ + (size_t)C_ * C_;
  bf16* WtV = WtK + (size_t)C_ * C_;
  bf16* WtO = WtV + (size_t)C_ * C_;
  bf16* xb  = WtO + (size_t)C_ * C_;           // [4096][1024]
  bf16* qkb = xb + (size_t)M_ * C_;            // [4096][2048]  (Q | K)
  bf16* vtb = qkb + (size_t)M_ * 2 * C_;       // [32][64][2048] V transposed
  bf16* yb  = vtb + (size_t)M_ * C_;           // [4096][1024]

  cvt_f32_bf16<<<dim3(M_ * C_ / (256 * 8)), 256, 0, stream>>>(x, xb);

  TP tp;
  tp.in[0] = Wq; tp.in[1] = Wk; tp.in[2] = Wv; tp.in[3] = Wo;
  tp.out[0] = WtQ; tp.out[1] = WtK; tp.out[2] = WtV; tp.out[3] = WtO;
  transpose4<<<dim3(32, 32, 4), 256, 0, stream>>>(tp);

  // fused QKV projection; V written transposed straight into vtb
  GArgs<bf16> gq;
  gq.A = xb; gq.Bt = WtQ;
  gq.bias[0] = bq; gq.bias[1] = bk; gq.bias[2] = bv;
  gq.Cout = qkb; gq.vt = vtb; gq.N = 2 * C_; gq.K = C_; gq.split = 1;
  gemm128<bf16><<<dim3(24, 32), 256, 0, stream>>>(gq);

  attn3<<<dim3(32, 16), 256, 0, stream>>>(qkb, vtb, yb);

  GArgs<float> go;
  go.A = yb; go.Bt = WtO;
  go.bias[0] = bo; go.bias[1] = bo; go.bias[2] = bo;
  go.Cout = (float*)d_out; go.vt = nullptr; go.N = C_; go.K = C_; go.split = 0;
  gemm128<float><<<dim3(8, 32), 256, 0, stream>>>(go);
}

// Round 7
// 219.233 us; speedup vs baseline: 1.6379x; 1.0302x over previous
//
#include <hip/hip_runtime.h>
#include <hip/hip_bf16.h>

typedef __bf16 bf16;
typedef __bf16 bf16x2 __attribute__((ext_vector_type(2)));
typedef __bf16 bf16x4 __attribute__((ext_vector_type(4)));
typedef __bf16 bf16x8 __attribute__((ext_vector_type(8)));
typedef float floatx4 __attribute__((ext_vector_type(4)));

#define B_ 2
#define T_ 2048
#define C_ 1024
#define H_ 16
#define D_ 64
#define M_ 4096
#define QK_LD 2048

__device__ __forceinline__ void load_lds16(const void* g, void* l) {
  __builtin_amdgcn_global_load_lds(
      (const __attribute__((address_space(1))) unsigned int*)g,
      (__attribute__((address_space(3))) unsigned int*)l, 16, 0, 0);
}

// --------------------------- prep: weight transposes + x convert (one launch)
struct PrepArgs { const float* w[4]; bf16* wt[4]; const float* x; bf16* xb; };

__global__ __launch_bounds__(256)
void prep(PrepArgs p) {
  const int bid = blockIdx.x;
  if (bid < 4096) {  // weight transpose+convert: z*1024 + y*32 + x
    __shared__ float tile[32][33];
    const int z = bid >> 10, xy = bid & 1023;
    const int bx = xy & 31, by = xy >> 5;
    const float* in = p.w[z];
    bf16* out = p.wt[z];
    int tx = threadIdx.x & 31, ty = threadIdx.x >> 5;
    int n0 = bx * 32, k0 = by * 32;
#pragma unroll
    for (int j = 0; j < 32; j += 8)
      tile[ty + j][tx] = in[(size_t)(k0 + ty + j) * C_ + n0 + tx];
    __syncthreads();
#pragma unroll
    for (int j = 0; j < 32; j += 8)
      out[(size_t)(n0 + ty + j) * C_ + k0 + tx] = (bf16)tile[tx][ty + j];
  } else {  // x fp32 -> bf16
    int i = ((bid - 4096) * 256 + threadIdx.x) * 8;
    float4 a = *(const float4*)(p.x + i);
    float4 b = *(const float4*)(p.x + i + 4);
    bf16x8 o;
    o[0] = (bf16)a.x; o[1] = (bf16)a.y; o[2] = (bf16)a.z; o[3] = (bf16)a.w;
    o[4] = (bf16)b.x; o[5] = (bf16)b.y; o[6] = (bf16)b.z; o[7] = (bf16)b.w;
    *(bf16x8*)(p.xb + i) = o;
  }
}

// ---------------------------------------------------------------- GEMM
// split mode: cols >=2048 (the V projection) are written transposed into
// vt[bh][d][T]; cols <2048 go to qk with leading dim g.N. Wave-uniform branch.
template <typename OutT>
struct GArgs {
  const bf16* A; const bf16* Bt;
  const float* bias[3];
  OutT* Cout; bf16* vt; int N; int K; int split;
};

template <typename OutT>
__global__ __launch_bounds__(256, 2)
void gemm128(GArgs<OutT> g) {
  __shared__ __align__(16) bf16 As[128 * 64];
  __shared__ __align__(16) bf16 Bs[128 * 64];
  const int tid = threadIdx.x;
  const int wave = tid >> 6, lane = tid & 63;
  const int quad = lane >> 4, l16 = lane & 15;
  const int m0 = blockIdx.y * 128, n0 = blockIdx.x * 128;
  const int wm = (wave >> 1) * 64, wn = (wave & 1) * 64;

  floatx4 acc[4][4] = {};

  int rA[4], cA[4];
#pragma unroll
  for (int t = 0; t < 4; ++t) {
    int pch = (wave * 4 + t) * 64 + lane;
    rA[t] = pch >> 3;
    cA[t] = (pch & 7) ^ (rA[t] & 7);
  }

  for (int k0 = 0; k0 < g.K; k0 += 64) {
    __syncthreads();
#pragma unroll
    for (int t = 0; t < 4; ++t) {
      load_lds16(g.A + (size_t)(m0 + rA[t]) * g.K + k0 + cA[t] * 8,
                 As + (wave * 4 + t) * 512);
      load_lds16(g.Bt + (size_t)(n0 + rA[t]) * g.K + k0 + cA[t] * 8,
                 Bs + (wave * 4 + t) * 512);
    }
    __syncthreads();
#pragma unroll
    for (int s = 0; s < 2; ++s) {
      bf16x8 af[4], bfr[4];
#pragma unroll
      for (int i = 0; i < 4; ++i) {
        int mr = wm + i * 16 + l16;
        af[i] = *(const bf16x8*)(As + ((mr * 8) + ((s * 4 + quad) ^ (mr & 7))) * 8);
        int nr = wn + i * 16 + l16;
        bfr[i] = *(const bf16x8*)(Bs + ((nr * 8) + ((s * 4 + quad) ^ (nr & 7))) * 8);
      }
#pragma unroll
      for (int i = 0; i < 4; ++i)
#pragma unroll
        for (int j = 0; j < 4; ++j)
          acc[i][j] = __builtin_amdgcn_mfma_f32_16x16x32_bf16(af[i], bfr[j],
                                                              acc[i][j], 0, 0, 0);
    }
  }

  const bool vsplit = g.split && (n0 >= 2048);
#pragma unroll
  for (int j = 0; j < 4; ++j) {
    int col = n0 + wn + j * 16 + l16;
    const float* bp = g.bias[col >> 10];
    float bv = bp[col & 1023];
    if (vsplit) {
      int cv = col - 2048;  // cv = h*64 + d
      bf16* dst0 = g.vt + ((size_t)((m0 >> 11) * 16 + (cv >> 6)) * 64 + (cv & 63)) * (size_t)T_
                   + (m0 & 2047) + wm + quad * 4;
#pragma unroll
      for (int i = 0; i < 4; ++i) {
        bf16x4 pk;
#pragma unroll
        for (int r = 0; r < 4; ++r) pk[r] = (bf16)(acc[i][j][r] + bv);
        *(bf16x4*)(dst0 + i * 16) = pk;
      }
    } else {
#pragma unroll
      for (int i = 0; i < 4; ++i) {
#pragma unroll
        for (int r = 0; r < 4; ++r) {
          int row = m0 + wm + i * 16 + quad * 4 + r;
          g.Cout[(size_t)row * g.N + col] = (OutT)(acc[i][j][r] + bv);
        }
      }
    }
  }
}

// ---------------------------------------------------------------- attention
// grid (32 bh, 16 q-tiles); block 256 = 4 waves x 32 Q rows.  K-tile 64.
// Double-buffered staging: loads for tile i+1 issued before computing tile i,
// drained (vmcnt0 + barrier) after.  K/V fragments hoisted out of the qt loop.
// l-state rides a 5th accumulator via a ones B-fragment.  No wave-divergent
// barriers; fully-masked subtiles contribute exactly 0 (P=0, alpha=1).
__global__ __launch_bounds__(256, 2)
void attn4(const bf16* __restrict__ qk, const bf16* __restrict__ vt,
           bf16* __restrict__ y) {
  __shared__ __align__(16) bf16 Kl[2][64 * 64];
  __shared__ __align__(16) bf16 Vl[2][64 * 64];
  __shared__ __align__(16) bf16 Pl[4][16 * 68];  // per-wave [row16][col64+4]
  const int tid = threadIdx.x, wave = tid >> 6, lane = tid & 63;
  const int quad = lane >> 4, l16 = lane & 15;
  const int bh = blockIdx.x, b = bh >> 4, h = bh & 15;
  const int qb = (blockIdx.y < 8) ? 15 - (int)blockIdx.y : (int)blockIdx.y - 8;
  const float L2E = 1.4426950408889634f;
  const float slope2 = exp2f(-0.5f * (float)(h + 1)) * L2E;  // log2-domain slope
  const float scl2 = 0.125f * L2E;
  const float NINF = -__builtin_inff();

  bf16x8 ones;
  {
    bf16 v1 = (l16 == 0) ? (bf16)1.0f : (bf16)0.0f;
#pragma unroll
    for (int j = 0; j < 8; ++j) ones[j] = v1;
  }

  int rS[2], cS[2];
#pragma unroll
  for (int t = 0; t < 2; ++t) {
    int p = t * 256 + tid;
    rS[t] = p >> 3;
    cS[t] = (p & 7) ^ (rS[t] & 7);
  }
  const bf16* kbase = qk + (size_t)b * T_ * QK_LD + 1024 + h * 64;
  const bf16* vbase = vt + (size_t)bh * 64 * T_;

  bf16* Plw = Pl[wave];
  const int q0 = qb * 128;
  const int w0 = q0 + wave * 32;

  bf16x8 qf[2][2];
#pragma unroll
  for (int qt = 0; qt < 2; ++qt)
#pragma unroll
    for (int s = 0; s < 2; ++s)
      qf[qt][s] = *(const bf16x8*)(qk +
          (size_t)(b * T_ + w0 + qt * 16 + l16) * QK_LD + h * 64 + s * 32 + quad * 8);

  float mrow[2][4];
  floatx4 o[2][5];
#pragma unroll
  for (int qt = 0; qt < 2; ++qt) {
#pragma unroll
    for (int r = 0; r < 4; ++r) mrow[qt][r] = NINF;
#pragma unroll
    for (int n = 0; n < 5; ++n) o[qt][n] = (floatx4)0.f;
  }

  const int niter = qb * 2 + 2;

  // prologue: stage tile 0 into buffer 0
#pragma unroll
  for (int t = 0; t < 2; ++t) {
    load_lds16(kbase + (size_t)rS[t] * QK_LD + cS[t] * 8, Kl[0] + (t * 4 + wave) * 512);
    load_lds16(vbase + (size_t)rS[t] * T_ + cS[t] * 8,    Vl[0] + (t * 4 + wave) * 512);
  }
  __builtin_amdgcn_s_waitcnt(0x0f70);  // vmcnt(0)
  __syncthreads();

  for (int it = 0; it < niter; ++it) {
    const int kj0 = it * 64;
    const int cur = it & 1;

    // issue async loads for tile it+1 into the other buffer (no wait yet)
    if (it + 1 < niter) {
      const int nk = kj0 + 64;
#pragma unroll
      for (int t = 0; t < 2; ++t) {
        load_lds16(kbase + (size_t)(nk + rS[t]) * QK_LD + cS[t] * 8,
                   Kl[cur ^ 1] + (t * 4 + wave) * 512);
        load_lds16(vbase + (size_t)rS[t] * T_ + nk + cS[t] * 8,
                   Vl[cur ^ 1] + (t * 4 + wave) * 512);
      }
    }

    // hoisted K/V fragments (qt-invariant)
    const bf16* Klc = Kl[cur];
    const bf16* Vlc = Vl[cur];
    bf16x8 kf[2][4], vf[2][4];
#pragma unroll
    for (int ss = 0; ss < 2; ++ss)
#pragma unroll
      for (int kt = 0; kt < 4; ++kt) {
        const int krow = kt * 16 + l16;
        kf[ss][kt] = *(const bf16x8*)(Klc + krow * 64 + (((ss * 4 + quad) ^ (krow & 7)) * 8));
        const int vrow = krow;
        vf[ss][kt] = *(const bf16x8*)(Vlc + vrow * 64 + (((ss * 4 + quad) ^ (vrow & 7)) * 8));
      }

    float scol[4];
#pragma unroll
    for (int kt = 0; kt < 4; ++kt)
      scol[kt] = slope2 * (float)(kj0 + kt * 16 + l16);

#pragma unroll
    for (int qt = 0; qt < 2; ++qt) {
      const int rb = w0 + qt * 16;
      floatx4 sa[4] = {};
#pragma unroll
      for (int ss = 0; ss < 2; ++ss)
#pragma unroll
        for (int kt = 0; kt < 4; ++kt)
          sa[kt] = __builtin_amdgcn_mfma_f32_16x16x32_bf16(qf[qt][ss], kf[ss][kt],
                                                           sa[kt], 0, 0, 0);

      float v[4][4], tm[4];
      if (kj0 + 63 > rb) {
#pragma unroll
        for (int r = 0; r < 4; ++r) {
          const int row = rb + quad * 4 + r;
          float m2 = NINF;
#pragma unroll
          for (int kt = 0; kt < 4; ++kt) {
            float val = fmaf(sa[kt][r], scl2, scol[kt]);
            if (kj0 + kt * 16 + l16 > row) val = NINF;
            v[kt][r] = val;
            m2 = fmaxf(m2, val);
          }
          tm[r] = m2;
        }
      } else {
#pragma unroll
        for (int r = 0; r < 4; ++r) {
          float m2 = NINF;
#pragma unroll
          for (int kt = 0; kt < 4; ++kt) {
            float val = fmaf(sa[kt][r], scl2, scol[kt]);
            v[kt][r] = val;
            m2 = fmaxf(m2, val);
          }
          tm[r] = m2;
        }
      }
#pragma unroll
      for (int off = 1; off < 16; off <<= 1)
#pragma unroll
        for (int r = 0; r < 4; ++r)
          tm[r] = fmaxf(tm[r], __shfl_xor(tm[r], off));

      float al[4];
#pragma unroll
      for (int r = 0; r < 4; ++r) {
        float mn = fmaxf(mrow[qt][r], tm[r]);   // finite after it=0 even if tm=-inf
        al[r] = __builtin_amdgcn_exp2f(mrow[qt][r] - mn);
        mrow[qt][r] = mn;
      }
      // P store in A-layout [row][col] (stride 68: conflict-free scalar writes)
#pragma unroll
      for (int kt = 0; kt < 4; ++kt)
#pragma unroll
        for (int r = 0; r < 4; ++r)
          Plw[(quad * 4 + r) * 68 + kt * 16 + l16] =
              (bf16)__builtin_amdgcn_exp2f(v[kt][r] - mrow[qt][r]);
#pragma unroll
      for (int n = 0; n < 5; ++n)
#pragma unroll
        for (int r = 0; r < 4; ++r) o[qt][n][r] *= al[r];

      __builtin_amdgcn_s_waitcnt(0xc07f);  // lgkmcnt(0): P writes visible in-wave

#pragma unroll
      for (int half = 0; half < 2; ++half) {
        bf16x8 pf = *(const bf16x8*)(Plw + l16 * 68 + half * 32 + quad * 8);
#pragma unroll
        for (int nt = 0; nt < 4; ++nt)
          o[qt][nt] = __builtin_amdgcn_mfma_f32_16x16x32_bf16(pf, vf[half][nt],
                                                              o[qt][nt], 0, 0, 0);
        o[qt][4] = __builtin_amdgcn_mfma_f32_16x16x32_bf16(pf, ones, o[qt][4], 0, 0, 0);
      }
    }

    __builtin_amdgcn_s_waitcnt(0x0f70);  // vmcnt(0): next tile's loads landed
    __syncthreads();                      // all waves done with cur, next ready
  }

#pragma unroll
  for (int qt = 0; qt < 2; ++qt)
#pragma unroll
    for (int r = 0; r < 4; ++r) {
      float lsum = __shfl(o[qt][4][r], lane & 48);  // broadcast from l16==0 of quad
      float inv = 1.f / lsum;
      const int row = w0 + qt * 16 + quad * 4 + r;
#pragma unroll
      for (int nt = 0; nt < 4; ++nt)
        y[(size_t)(b * T_ + row) * C_ + h * 64 + nt * 16 + l16] =
            (bf16)(o[qt][nt][r] * inv);
    }
}

// ---------------------------------------------------------------- launch
extern "C" void kernel_launch(void* const* d_in, const int* in_sizes, int n_in,
                              void* d_out, int out_size, void* d_ws, size_t ws_size,
                              hipStream_t stream) {
  const float* x  = (const float*)d_in[0];
  const float* Wq = (const float*)d_in[1];
  const float* bq = (const float*)d_in[2];
  const float* Wk = (const float*)d_in[3];
  const float* bk = (const float*)d_in[4];
  const float* Wv = (const float*)d_in[5];
  const float* bv = (const float*)d_in[6];
  const float* Wo = (const float*)d_in[7];
  const float* bo = (const float*)d_in[8];

  bf16* ws  = (bf16*)d_ws;
  bf16* WtQ = ws;                              // weights^T, bf16, [1024][1024] each
  bf16* WtK = WtQ + (size_t)C_ * C_;
  bf16* WtV = WtK + (size_t)C_ * C_;
  bf16* WtO = WtV + (size_t)C_ * C_;
  bf16* xb  = WtO + (size_t)C_ * C_;           // [4096][1024]
  bf16* qkb = xb + (size_t)M_ * C_;            // [4096][2048]  (Q | K)
  bf16* vtb = qkb + (size_t)M_ * 2 * C_;       // [32][64][2048] V transposed
  bf16* yb  = vtb + (size_t)M_ * C_;           // [4096][1024]

  PrepArgs pp;
  pp.w[0] = Wq; pp.w[1] = Wk; pp.w[2] = Wv; pp.w[3] = Wo;
  pp.wt[0] = WtQ; pp.wt[1] = WtK; pp.wt[2] = WtV; pp.wt[3] = WtO;
  pp.x = x; pp.xb = xb;
  prep<<<dim3(4096 + M_ * C_ / (256 * 8)), 256, 0, stream>>>(pp);

  // fused QKV projection; V written transposed straight into vtb
  GArgs<bf16> gq;
  gq.A = xb; gq.Bt = WtQ;
  gq.bias[0] = bq; gq.bias[1] = bk; gq.bias[2] = bv;
  gq.Cout = qkb; gq.vt = vtb; gq.N = 2 * C_; gq.K = C_; gq.split = 1;
  gemm128<bf16><<<dim3(24, 32), 256, 0, stream>>>(gq);

  attn4<<<dim3(32, 16), 256, 0, stream>>>(qkb, vtb, yb);

  GArgs<float> go;
  go.A = yb; go.Bt = WtO;
  go.bias[0] = bo; go.bias[1] = bo; go.bias[2] = bo;
  go.Cout = (float*)d_out; go.vt = nullptr; go.N = C_; go.K = C_; go.split = 0;
  gemm128<float><<<dim3(8, 32), 256, 0, stream>>>(go);
}

// Round 8
// 205.370 us; speedup vs baseline: 1.7485x; 1.0675x over previous
//
#include <hip/hip_runtime.h>
#include <hip/hip_bf16.h>

typedef __bf16 bf16;
typedef __bf16 bf16x2 __attribute__((ext_vector_type(2)));
typedef __bf16 bf16x4 __attribute__((ext_vector_type(4)));
typedef __bf16 bf16x8 __attribute__((ext_vector_type(8)));
typedef float floatx4 __attribute__((ext_vector_type(4)));

#define B_ 2
#define T_ 2048
#define C_ 1024
#define H_ 16
#define D_ 64
#define M_ 4096
#define QK_LD 2048

__device__ __forceinline__ void load_lds16(const void* g, void* l) {
  __builtin_amdgcn_global_load_lds(
      (const __attribute__((address_space(1))) unsigned int*)g,
      (__attribute__((address_space(3))) unsigned int*)l, 16, 0, 0);
}

// --------------------------- prep: weight transposes + x convert (one launch)
struct PrepArgs { const float* w[4]; bf16* wt[4]; const float* x; bf16* xb; };

__global__ __launch_bounds__(256)
void prep(PrepArgs p) {
  const int bid = blockIdx.x;
  if (bid < 4096) {
    __shared__ float tile[32][33];
    const int z = bid >> 10, xy = bid & 1023;
    const int bx = xy & 31, by = xy >> 5;
    const float* in = p.w[z];
    bf16* out = p.wt[z];
    int tx = threadIdx.x & 31, ty = threadIdx.x >> 5;
    int n0 = bx * 32, k0 = by * 32;
#pragma unroll
    for (int j = 0; j < 32; j += 8)
      tile[ty + j][tx] = in[(size_t)(k0 + ty + j) * C_ + n0 + tx];
    __syncthreads();
#pragma unroll
    for (int j = 0; j < 32; j += 8)
      out[(size_t)(n0 + ty + j) * C_ + k0 + tx] = (bf16)tile[tx][ty + j];
  } else {
    int i = ((bid - 4096) * 256 + threadIdx.x) * 8;
    float4 a = *(const float4*)(p.x + i);
    float4 b = *(const float4*)(p.x + i + 4);
    bf16x8 o;
    o[0] = (bf16)a.x; o[1] = (bf16)a.y; o[2] = (bf16)a.z; o[3] = (bf16)a.w;
    o[4] = (bf16)b.x; o[5] = (bf16)b.y; o[6] = (bf16)b.z; o[7] = (bf16)b.w;
    *(bf16x8*)(p.xb + i) = o;
  }
}

// ---------------------------------------------------------------- QKV GEMM
// 128x128 tile; cols >=2048 (V) written transposed into vt[bh][d][T].
struct GQ {
  const bf16* A; const bf16* Bt;
  const float* bias[3];
  bf16* Cout; bf16* vt; int N; int K;
};

__global__ __launch_bounds__(256, 2)
void gemm128(GQ g) {
  __shared__ __align__(16) bf16 As[128 * 64];
  __shared__ __align__(16) bf16 Bs[128 * 64];
  const int tid = threadIdx.x;
  const int wave = tid >> 6, lane = tid & 63;
  const int quad = lane >> 4, l16 = lane & 15;
  const int m0 = blockIdx.y * 128, n0 = blockIdx.x * 128;
  const int wm = (wave >> 1) * 64, wn = (wave & 1) * 64;

  floatx4 acc[4][4] = {};

  int rA[4], cA[4];
#pragma unroll
  for (int t = 0; t < 4; ++t) {
    int pch = (wave * 4 + t) * 64 + lane;
    rA[t] = pch >> 3;
    cA[t] = (pch & 7) ^ (rA[t] & 7);
  }

  for (int k0 = 0; k0 < g.K; k0 += 64) {
    __syncthreads();
#pragma unroll
    for (int t = 0; t < 4; ++t) {
      load_lds16(g.A + (size_t)(m0 + rA[t]) * g.K + k0 + cA[t] * 8,
                 As + (wave * 4 + t) * 512);
      load_lds16(g.Bt + (size_t)(n0 + rA[t]) * g.K + k0 + cA[t] * 8,
                 Bs + (wave * 4 + t) * 512);
    }
    __builtin_amdgcn_s_waitcnt(0x0f70);
    __syncthreads();
#pragma unroll
    for (int s = 0; s < 2; ++s) {
      bf16x8 af[4], bfr[4];
#pragma unroll
      for (int i = 0; i < 4; ++i) {
        int mr = wm + i * 16 + l16;
        af[i] = *(const bf16x8*)(As + ((mr * 8) + ((s * 4 + quad) ^ (mr & 7))) * 8);
        int nr = wn + i * 16 + l16;
        bfr[i] = *(const bf16x8*)(Bs + ((nr * 8) + ((s * 4 + quad) ^ (nr & 7))) * 8);
      }
#pragma unroll
      for (int i = 0; i < 4; ++i)
#pragma unroll
        for (int j = 0; j < 4; ++j)
          acc[i][j] = __builtin_amdgcn_mfma_f32_16x16x32_bf16(af[i], bfr[j],
                                                              acc[i][j], 0, 0, 0);
    }
  }

  const bool vsplit = (n0 >= 2048);
#pragma unroll
  for (int j = 0; j < 4; ++j) {
    int col = n0 + wn + j * 16 + l16;
    const float* bp = g.bias[col >> 10];
    float bv = bp[col & 1023];
    if (vsplit) {
      int cv = col - 2048;  // cv = h*64 + d
      bf16* dst0 = g.vt + ((size_t)((m0 >> 11) * 16 + (cv >> 6)) * 64 + (cv & 63)) * (size_t)T_
                   + (m0 & 2047) + wm + quad * 4;
#pragma unroll
      for (int i = 0; i < 4; ++i) {
        bf16x4 pk;
#pragma unroll
        for (int r = 0; r < 4; ++r) pk[r] = (bf16)(acc[i][j][r] + bv);
        *(bf16x4*)(dst0 + i * 16) = pk;
      }
    } else {
#pragma unroll
      for (int i = 0; i < 4; ++i) {
#pragma unroll
        for (int r = 0; r < 4; ++r) {
          int row = m0 + wm + i * 16 + quad * 4 + r;
          g.Cout[(size_t)row * g.N + col] = (bf16)(acc[i][j][r] + bv);
        }
      }
    }
  }
}

// ---------------------------------------------------------------- out GEMM
// C[4096,1024](fp32) = A[4096,1024](bf16) @ Bt[1024,1024]^T + bias.
// 64x128 tile, grid (8,64)=512 blocks (2/CU).  4 waves 2x2 of 32x64.
__global__ __launch_bounds__(256, 2)
void gemm_out(const bf16* __restrict__ A, const bf16* __restrict__ Bt,
              const float* __restrict__ bias, float* __restrict__ C) {
  __shared__ __align__(16) bf16 As[64 * 64];
  __shared__ __align__(16) bf16 Bs[128 * 64];
  const int tid = threadIdx.x;
  const int wave = tid >> 6, lane = tid & 63;
  const int quad = lane >> 4, l16 = lane & 15;
  const int m0 = blockIdx.y * 64, n0 = blockIdx.x * 128;
  const int wm = (wave >> 1) * 32, wn = (wave & 1) * 64;

  floatx4 acc[2][4] = {};

  int rA[2], cA[2], rB[4], cB[4];
#pragma unroll
  for (int t = 0; t < 2; ++t) {
    int p = t * 256 + tid;
    rA[t] = p >> 3; cA[t] = (p & 7) ^ (rA[t] & 7);
  }
#pragma unroll
  for (int t = 0; t < 4; ++t) {
    int p = t * 256 + tid;
    rB[t] = p >> 3; cB[t] = (p & 7) ^ (rB[t] & 7);
  }

  for (int k0 = 0; k0 < 1024; k0 += 64) {
    __syncthreads();
#pragma unroll
    for (int t = 0; t < 2; ++t)
      load_lds16(A + (size_t)(m0 + rA[t]) * 1024 + k0 + cA[t] * 8,
                 As + t * 2048 + wave * 512);
#pragma unroll
    for (int t = 0; t < 4; ++t)
      load_lds16(Bt + (size_t)(n0 + rB[t]) * 1024 + k0 + cB[t] * 8,
                 Bs + t * 2048 + wave * 512);
    __builtin_amdgcn_s_waitcnt(0x0f70);
    __syncthreads();
#pragma unroll
    for (int s = 0; s < 2; ++s) {
      bf16x8 af[2], bfr[4];
#pragma unroll
      for (int i = 0; i < 2; ++i) {
        int mr = wm + i * 16 + l16;
        af[i] = *(const bf16x8*)(As + ((mr * 8) + ((s * 4 + quad) ^ (mr & 7))) * 8);
      }
#pragma unroll
      for (int j = 0; j < 4; ++j) {
        int nr = wn + j * 16 + l16;
        bfr[j] = *(const bf16x8*)(Bs + ((nr * 8) + ((s * 4 + quad) ^ (nr & 7))) * 8);
      }
#pragma unroll
      for (int i = 0; i < 2; ++i)
#pragma unroll
        for (int j = 0; j < 4; ++j)
          acc[i][j] = __builtin_amdgcn_mfma_f32_16x16x32_bf16(af[i], bfr[j],
                                                              acc[i][j], 0, 0, 0);
    }
  }

#pragma unroll
  for (int j = 0; j < 4; ++j) {
    int col = n0 + wn + j * 16 + l16;
    float bv = bias[col];
#pragma unroll
    for (int i = 0; i < 2; ++i)
#pragma unroll
      for (int r = 0; r < 4; ++r) {
        int row = m0 + wm + i * 16 + quad * 4 + r;
        C[(size_t)row * 1024 + col] = acc[i][j][r] + bv;
      }
  }
}

// ---------------------------------------------------------------- attention
// grid (32 bh, 24): y<8 -> whole q-tile qb=y; y in [8,16) -> qb=23-y seg0
// (k-tiles [0,qb+1), never masked); y in [16,24) -> qb=31-y seg1
// (k-tiles [qb+1,2qb+2), diagonal).  CU triples (y,y+8,y+16) each sum to 34
// iters.  Segments write unnormalized O(bf16) + per-row m,l(fp32, log2
// domain); combine kernel merges.  Double-buffered staging; no divergent
// barriers; uniform trip counts.
__global__ __launch_bounds__(256, 2)
void attn5(const bf16* __restrict__ qk, const bf16* __restrict__ vt,
           bf16* __restrict__ y, bf16* __restrict__ po,
           float* __restrict__ pm, float* __restrict__ pl) {
  __shared__ __align__(16) bf16 Kl[2][64 * 64];
  __shared__ __align__(16) bf16 Vl[2][64 * 64];
  __shared__ __align__(16) bf16 Pl[4][16 * 68];
  const int tid = threadIdx.x, wave = tid >> 6, lane = tid & 63;
  const int quad = lane >> 4, l16 = lane & 15;
  const int bh = blockIdx.x, b = bh >> 4, h = bh & 15;
  const int yy = blockIdx.y;
  int qb, kbeg, kcnt, seg;
  if (yy < 8)       { qb = yy;      kbeg = 0;      kcnt = 2 * qb + 2; seg = -1; }
  else if (yy < 16) { qb = 23 - yy; kbeg = 0;      kcnt = qb + 1;     seg = 0;  }
  else              { qb = 31 - yy; kbeg = qb + 1; kcnt = qb + 1;     seg = 1;  }
  const float L2E = 1.4426950408889634f;
  const float slope2 = exp2f(-0.5f * (float)(h + 1)) * L2E;
  const float scl2 = 0.125f * L2E;
  const float NINF = -__builtin_inff();

  bf16x8 ones;
  {
    bf16 v1 = (l16 == 0) ? (bf16)1.0f : (bf16)0.0f;
#pragma unroll
    for (int j = 0; j < 8; ++j) ones[j] = v1;
  }

  int rS[2], cS[2];
#pragma unroll
  for (int t = 0; t < 2; ++t) {
    int p = t * 256 + tid;
    rS[t] = p >> 3;
    cS[t] = (p & 7) ^ (rS[t] & 7);
  }
  const bf16* kbase = qk + (size_t)b * T_ * QK_LD + 1024 + h * 64;
  const bf16* vbase = vt + (size_t)bh * 64 * T_;

  bf16* Plw = Pl[wave];
  const int q0 = qb * 128;
  const int w0 = q0 + wave * 32;

  bf16x8 qf[2][2];
#pragma unroll
  for (int qt = 0; qt < 2; ++qt)
#pragma unroll
    for (int s = 0; s < 2; ++s)
      qf[qt][s] = *(const bf16x8*)(qk +
          (size_t)(b * T_ + w0 + qt * 16 + l16) * QK_LD + h * 64 + s * 32 + quad * 8);

  float mrow[2][4];
  floatx4 o[2][5];
#pragma unroll
  for (int qt = 0; qt < 2; ++qt) {
#pragma unroll
    for (int r = 0; r < 4; ++r) mrow[qt][r] = NINF;
#pragma unroll
    for (int n = 0; n < 5; ++n) o[qt][n] = (floatx4)0.f;
  }

  // prologue: stage first tile into buffer 0
#pragma unroll
  for (int t = 0; t < 2; ++t) {
    load_lds16(kbase + (size_t)(kbeg * 64 + rS[t]) * QK_LD + cS[t] * 8,
               Kl[0] + (t * 4 + wave) * 512);
    load_lds16(vbase + (size_t)rS[t] * T_ + kbeg * 64 + cS[t] * 8,
               Vl[0] + (t * 4 + wave) * 512);
  }
  __builtin_amdgcn_s_waitcnt(0x0f70);
  __syncthreads();

  for (int it = 0; it < kcnt; ++it) {
    const int kj0 = (kbeg + it) * 64;
    const int cur = it & 1;

    if (it + 1 < kcnt) {
      const int nk = kj0 + 64;
#pragma unroll
      for (int t = 0; t < 2; ++t) {
        load_lds16(kbase + (size_t)(nk + rS[t]) * QK_LD + cS[t] * 8,
                   Kl[cur ^ 1] + (t * 4 + wave) * 512);
        load_lds16(vbase + (size_t)rS[t] * T_ + nk + cS[t] * 8,
                   Vl[cur ^ 1] + (t * 4 + wave) * 512);
      }
    }

    const bf16* Klc = Kl[cur];
    const bf16* Vlc = Vl[cur];
    bf16x8 kf[2][4], vf[2][4];
#pragma unroll
    for (int ss = 0; ss < 2; ++ss)
#pragma unroll
      for (int kt = 0; kt < 4; ++kt) {
        const int krow = kt * 16 + l16;
        kf[ss][kt] = *(const bf16x8*)(Klc + krow * 64 + (((ss * 4 + quad) ^ (krow & 7)) * 8));
        vf[ss][kt] = *(const bf16x8*)(Vlc + krow * 64 + (((ss * 4 + quad) ^ (krow & 7)) * 8));
      }

    float scol[4];
#pragma unroll
    for (int kt = 0; kt < 4; ++kt)
      scol[kt] = slope2 * (float)(kj0 + kt * 16 + l16);

#pragma unroll
    for (int qt = 0; qt < 2; ++qt) {
      const int rb = w0 + qt * 16;
      floatx4 sa[4] = {};
#pragma unroll
      for (int ss = 0; ss < 2; ++ss)
#pragma unroll
        for (int kt = 0; kt < 4; ++kt)
          sa[kt] = __builtin_amdgcn_mfma_f32_16x16x32_bf16(qf[qt][ss], kf[ss][kt],
                                                           sa[kt], 0, 0, 0);

      float v[4][4], tm[4];
      if (kj0 + 63 > rb) {
#pragma unroll
        for (int r = 0; r < 4; ++r) {
          const int row = rb + quad * 4 + r;
          float m2 = NINF;
#pragma unroll
          for (int kt = 0; kt < 4; ++kt) {
            float val = fmaf(sa[kt][r], scl2, scol[kt]);
            if (kj0 + kt * 16 + l16 > row) val = NINF;
            v[kt][r] = val;
            m2 = fmaxf(m2, val);
          }
          tm[r] = m2;
        }
      } else {
#pragma unroll
        for (int r = 0; r < 4; ++r) {
          float m2 = NINF;
#pragma unroll
          for (int kt = 0; kt < 4; ++kt) {
            float val = fmaf(sa[kt][r], scl2, scol[kt]);
            v[kt][r] = val;
            m2 = fmaxf(m2, val);
          }
          tm[r] = m2;
        }
      }
#pragma unroll
      for (int off = 1; off < 16; off <<= 1)
#pragma unroll
        for (int r = 0; r < 4; ++r)
          tm[r] = fmaxf(tm[r], __shfl_xor(tm[r], off));

      float al[4];
#pragma unroll
      for (int r = 0; r < 4; ++r) {
        float mn = fmaxf(mrow[qt][r], tm[r]);
        al[r] = __builtin_amdgcn_exp2f(mrow[qt][r] - mn);
        mrow[qt][r] = mn;
      }
#pragma unroll
      for (int kt = 0; kt < 4; ++kt)
#pragma unroll
        for (int r = 0; r < 4; ++r)
          Plw[(quad * 4 + r) * 68 + kt * 16 + l16] =
              (bf16)__builtin_amdgcn_exp2f(v[kt][r] - mrow[qt][r]);
#pragma unroll
      for (int n = 0; n < 5; ++n)
#pragma unroll
        for (int r = 0; r < 4; ++r) o[qt][n][r] *= al[r];

      __builtin_amdgcn_s_waitcnt(0xc07f);  // lgkmcnt(0): P visible in-wave

#pragma unroll
      for (int half = 0; half < 2; ++half) {
        bf16x8 pf = *(const bf16x8*)(Plw + l16 * 68 + half * 32 + quad * 8);
#pragma unroll
        for (int nt = 0; nt < 4; ++nt)
          o[qt][nt] = __builtin_amdgcn_mfma_f32_16x16x32_bf16(pf, vf[half][nt],
                                                              o[qt][nt], 0, 0, 0);
        o[qt][4] = __builtin_amdgcn_mfma_f32_16x16x32_bf16(pf, ones, o[qt][4], 0, 0, 0);
      }
    }

    __builtin_amdgcn_s_waitcnt(0x0f70);  // vmcnt(0): next tile landed
    __syncthreads();
  }

  if (seg < 0) {
#pragma unroll
    for (int qt = 0; qt < 2; ++qt)
#pragma unroll
      for (int r = 0; r < 4; ++r) {
        float lsum = __shfl(o[qt][4][r], lane & 48);
        float inv = 1.f / lsum;
        const int row = w0 + qt * 16 + quad * 4 + r;
#pragma unroll
        for (int nt = 0; nt < 4; ++nt)
          y[(size_t)(b * T_ + row) * C_ + h * 64 + nt * 16 + l16] =
              (bf16)(o[qt][nt][r] * inv);
      }
  } else {
    const int pid = (bh * 8 + (qb - 8)) * 2 + seg;
    bf16* pob = po + (size_t)pid * 128 * 64;
#pragma unroll
    for (int qt = 0; qt < 2; ++qt)
#pragma unroll
      for (int r = 0; r < 4; ++r) {
        const int rl = wave * 32 + qt * 16 + quad * 4 + r;
#pragma unroll
        for (int nt = 0; nt < 4; ++nt)
          pob[rl * 64 + nt * 16 + l16] = (bf16)o[qt][nt][r];
        if (l16 == 0) {
          pm[pid * 128 + rl] = mrow[qt][r];
          pl[pid * 128 + rl] = o[qt][4][r];
        }
      }
  }
}

// --------------------------------------------------- combine split segments
__global__ __launch_bounds__(256)
void combine(const bf16* __restrict__ po, const float* __restrict__ pm,
             const float* __restrict__ pl, bf16* __restrict__ y) {
  const int pidq = blockIdx.x;           // bh*8 + tq
  const int bh = pidq >> 3, qb = (pidq & 7) + 8;
  const int b = bh >> 4, h = bh & 15;
  const bf16* p0 = po + (size_t)(pidq * 2) * 128 * 64;
  const bf16* p1 = p0 + 128 * 64;
  const int col = threadIdx.x & 63, r0 = threadIdx.x >> 6;
#pragma unroll 4
  for (int i = 0; i < 32; ++i) {
    const int row = i * 4 + r0;
    float m0 = pm[(pidq * 2) * 128 + row], m1 = pm[(pidq * 2 + 1) * 128 + row];
    float l0 = pl[(pidq * 2) * 128 + row], l1 = pl[(pidq * 2 + 1) * 128 + row];
    float mm = fmaxf(m0, m1);
    float w0 = __builtin_amdgcn_exp2f(m0 - mm);
    float w1 = __builtin_amdgcn_exp2f(m1 - mm);
    float inv = 1.f / (w0 * l0 + w1 * l1);
    float val = (w0 * (float)p0[row * 64 + col] + w1 * (float)p1[row * 64 + col]) * inv;
    y[(size_t)(b * T_ + qb * 128 + row) * C_ + h * 64 + col] = (bf16)val;
  }
}

// ---------------------------------------------------------------- launch
extern "C" void kernel_launch(void* const* d_in, const int* in_sizes, int n_in,
                              void* d_out, int out_size, void* d_ws, size_t ws_size,
                              hipStream_t stream) {
  const float* x  = (const float*)d_in[0];
  const float* Wq = (const float*)d_in[1];
  const float* bq = (const float*)d_in[2];
  const float* Wk = (const float*)d_in[3];
  const float* bk = (const float*)d_in[4];
  const float* Wv = (const float*)d_in[5];
  const float* bv = (const float*)d_in[6];
  const float* Wo = (const float*)d_in[7];
  const float* bo = (const float*)d_in[8];

  bf16* ws  = (bf16*)d_ws;
  bf16* WtQ = ws;
  bf16* WtK = WtQ + (size_t)C_ * C_;
  bf16* WtV = WtK + (size_t)C_ * C_;
  bf16* WtO = WtV + (size_t)C_ * C_;
  bf16* xb  = WtO + (size_t)C_ * C_;           // [4096][1024]
  bf16* qkb = xb + (size_t)M_ * C_;            // [4096][2048]  (Q | K)
  bf16* vtb = qkb + (size_t)M_ * 2 * C_;       // [32][64][2048]
  bf16* yb  = vtb + (size_t)M_ * C_;           // [4096][1024]
  bf16* pob = yb + (size_t)M_ * C_;            // [512][128][64] partial O
  float* pmb = (float*)(pob + (size_t)512 * 128 * 64);
  float* plb = pmb + 512 * 128;

  PrepArgs pp;
  pp.w[0] = Wq; pp.w[1] = Wk; pp.w[2] = Wv; pp.w[3] = Wo;
  pp.wt[0] = WtQ; pp.wt[1] = WtK; pp.wt[2] = WtV; pp.wt[3] = WtO;
  pp.x = x; pp.xb = xb;
  prep<<<dim3(4096 + M_ * C_ / (256 * 8)), 256, 0, stream>>>(pp);

  GQ gq;
  gq.A = xb; gq.Bt = WtQ;
  gq.bias[0] = bq; gq.bias[1] = bk; gq.bias[2] = bv;
  gq.Cout = qkb; gq.vt = vtb; gq.N = 2 * C_; gq.K = C_;
  gemm128<<<dim3(24, 32), 256, 0, stream>>>(gq);

  attn5<<<dim3(32, 24), 256, 0, stream>>>(qkb, vtb, yb, pob, pmb, plb);
  combine<<<dim3(256), 256, 0, stream>>>(pob, pmb, plb, yb);

  gemm_out<<<dim3(8, 64), 256, 0, stream>>>(yb, WtO, bo, (float*)d_out);
}